// Round 7
// baseline (165.787 us; speedup 1.0000x reference)
//
#include <hip/hip_runtime.h>
#include <math.h>

// LogHarmonicLowering. floor(f + s_k) = f + D_k (constant int offsets per k).
// R7: R6's register pipeline (17 input half-rows in VGPRs -> 80 output
// half-rows), but with CACHED stores instead of nontemporal. Evidence: harness
// fill kernels (cached, pure write) run 6.7-6.85 TB/s while our NT-write-heavy
// mix capped at ~5.9 aggregate. Input is register-staged/read-once now, so L2
// write pollution is harmless; stores fully cover cache lines (no RFO).

#define CH   16
#define KK   5
#define FREQ 1024
#define T4   128

typedef float f32x4 __attribute__((ext_vector_type(4)));

// f32(200*(ln(0.001*(k+1)) - ln(0.001))), matching numpy f64 then f32 cast
__device__ __constant__ const float S_TAB[5] = {
    0.0f, 138.62943611198906f, 219.72245773362196f, 277.2588722239781f, 321.88758248682006f
};
#define D0 0
#define D1 138
#define D2 219
#define D3 277
#define D4 321

__global__ __launch_bounds__(256) void lhl_kernel(const float* __restrict__ x,
                                                  float* __restrict__ out) {
    const int tid  = (int)threadIdx.x;
    const int wave = tid >> 6, lane = tid & 63;
    const int bi   = (int)blockIdx.x;

    // strip = one wave's task: (slice, j-window, half-row)
    const int strip = bi * 4 + wave;        // 0..8191
    const int half  = strip & 1;
    const int j     = (strip >> 1) & 63;    // input rows [16j, 16j+17)
    const int slice = strip >> 7;           // b*16 + c
    const int b = slice >> 4, c = slice & 15;
    const int a = j << 4;

    const f32x4* __restrict__ xin = (const f32x4*)x;
    f32x4* __restrict__ o4 = (f32x4*)out;

    const size_t sbase = (size_t)slice << 17;
    const int col = (half << 6) + lane;     // t4 in [0,128)

    // ---- load 17 half-rows into registers (j==63: dup row 15, unused w1=0) ----
    const int nload = (j == 63) ? 16 : 17;
    f32x4 rows[17];
    #pragma unroll
    for (int r = 0; r < 17; ++r) {
        int rr = min(r, nload - 1);
        rows[r] = xin[sbase + ((size_t)(a + rr) << 7) + col];
    }

    // ---- emit 5 outputs per row-pair as loads arrive ----
    const int dtab[5] = {D0, D1, D2, D3, D4};
    #pragma unroll
    for (int r = 0; r < 16; ++r) {
        const int i0 = a + r;
        #pragma unroll
        for (int k = 0; k < KK; ++k) {
            const int f = i0 - dtab[k];
            if (f >= 0) {                           // wave-uniform
                float pos = (float)f + S_TAB[k];
                float w = pos - floorf(pos);        // == frac, reference-exact f32
                float w1 = (i0 + 1 < FREQ) ? w : 0.0f;
                f32x4 res = rows[r] * (1.0f - w) + rows[r + 1] * w1;
                size_t o = ((size_t)((b * KK + k) * CH + c) << 17)
                         + ((size_t)f << 7) + col;
                o4[o] = res;
            }
        }
    }

    // ---- zero tail: f in [1024-D_k, 1024), k=1..4 -> 955 rows/slice, split
    // over the 32 blocks of this slice (32*3820 = 955*128 f4 exactly) ----
    const int blkin = bi & 31;
    const f32x4 zero = {0.f, 0.f, 0.f, 0.f};
    for (int l = tid; l < 3820; l += 256) {
        int zz = blkin * 3820 + l;
        int zrow = zz >> 7, t4z = zz & 127;
        int k, f;
        if (zrow < 138)      { k = 1; f = (FREQ - D1) + zrow; }
        else if (zrow < 357) { k = 2; f = (FREQ - D2) + (zrow - 138); }
        else if (zrow < 634) { k = 3; f = (FREQ - D3) + (zrow - 357); }
        else                 { k = 4; f = (FREQ - D4) + (zrow - 634); }
        size_t o = ((size_t)((b * KK + k) * CH + c) << 17) + ((size_t)f << 7) + t4z;
        o4[o] = zero;
    }
}

extern "C" void kernel_launch(void* const* d_in, const int* in_sizes, int n_in,
                              void* d_out, int out_size, void* d_ws, size_t ws_size,
                              hipStream_t stream) {
    const float* x = (const float*)d_in[0];
    float* out = (float*)d_out;
    lhl_kernel<<<2048, 256, 0, stream>>>(x, out);   // 8192 wave-strips
}

// Round 8
// 142.763 us; speedup vs baseline: 1.1613x; 1.1613x over previous
//
#include <hip/hip_runtime.h>

// LogHarmonicLowering. floor(f + s_k) = f + D_k, and w = frac(f+s_k) ~= frac(s_k)
// is CONSTANT per k (f integer; f32 sum-rounding deviates <=1.2e-4, never crosses
// an integer; output error ~5e-4 << 0.108 threshold).
// R8: R6's NT register pipeline with (a) 9-row windows (36 data VGPRs, was 68)
// and (b) compile-time interpolation weights (no floorf/table) -> VGPR well
// under 128 for 16-32 waves/CU. NT stores (R7 proved cached regresses).

#define CH   16
#define KK   5
#define FREQ 1024

typedef float f32x4 __attribute__((ext_vector_type(4)));

#define D1 138
#define D2 219
#define D3 277
#define D4 321
// B_k = frac(s_k), A_k = 1 - B_k (f64 -> f32)
#define B1 0.62943611f
#define B2 0.72245773f
#define B3 0.25887222f
#define B4 0.88758249f
#define A1 0.37056389f
#define A2 0.27754227f
#define A3 0.74112778f
#define A4 0.11241751f

__global__ __launch_bounds__(256) void lhl_kernel(const float* __restrict__ x,
                                                  float* __restrict__ out) {
    const int tid  = (int)threadIdx.x;
    const int wave = tid >> 6, lane = tid & 63;
    const int bi   = (int)blockIdx.x;

    // strip = (slice, jwin in [0,128), half): 64*128*2 = 16384 strips, 4/block
    const int strip = bi * 4 + wave;
    const int half  = strip & 1;
    const int jwin  = (strip >> 1) & 127;   // input rows [8*jwin, 8*jwin+9)
    const int slice = strip >> 8;           // b*16 + c
    const int b = slice >> 4, c = slice & 15;
    const int a = jwin << 3;

    const f32x4* __restrict__ xin = (const f32x4*)x;
    f32x4* __restrict__ o4 = (f32x4*)out;

    const int col = (half << 6) + lane;     // t4 in [0,128)
    const size_t sbase = (size_t)slice << 17;

    // ---- load 9 half-rows into registers (clamp at row 1023; dup is harmless:
    // its consumer has weight 0) ----
    f32x4 rows[9];
    #pragma unroll
    for (int r = 0; r < 9; ++r) {
        int rr = min(a + r, FREQ - 1);
        rows[r] = xin[sbase + ((size_t)rr << 7) + col];
    }

    // ---- 5 output plane bases for this (b,*,c) ----
    size_t pb[KK];
    #pragma unroll
    for (int k = 0; k < KK; ++k)
        pb[k] = (size_t)((b * KK + k) * CH + c) << 17;

    const int   dtab[KK] = {0, D1, D2, D3, D4};
    const float wA[KK]   = {1.0f, A1, A2, A3, A4};
    const float wB[KK]   = {0.0f, B1, B2, B3, B4};

    #pragma unroll
    for (int r = 0; r < 8; ++r) {
        const int i0 = a + r;
        // k = 0: exact copy
        __builtin_nontemporal_store(rows[r], o4 + pb[0] + ((size_t)i0 << 7) + col);
        #pragma unroll
        for (int k = 1; k < KK; ++k) {
            const int f = i0 - dtab[k];
            if (f >= 0) {                                  // wave-uniform
                const float bb = (i0 == FREQ - 1) ? 0.0f : wB[k];
                f32x4 res = rows[r] * wA[k] + rows[r + 1] * bb;
                __builtin_nontemporal_store(res, o4 + pb[k] + ((size_t)f << 7) + col);
            }
        }
    }

    // ---- zero tail: f in [1024-D_k, 1024), k=1..4 -> 955 rows * 128 f4 per
    // slice, split over the 64 blocks of this slice (64*1910 = 122240 exactly) ----
    const int blkin = bi & 63;
    const f32x4 zero = {0.f, 0.f, 0.f, 0.f};
    for (int l = tid; l < 1910; l += 256) {
        int zz = blkin * 1910 + l;
        int zrow = zz >> 7, t4z = zz & 127;
        int k, f;
        if (zrow < 138)      { k = 1; f = (FREQ - D1) + zrow; }
        else if (zrow < 357) { k = 2; f = (FREQ - D2) + (zrow - 138); }
        else if (zrow < 634) { k = 3; f = (FREQ - D3) + (zrow - 357); }
        else                 { k = 4; f = (FREQ - D4) + (zrow - 634); }
        size_t o = pb[k] + ((size_t)f << 7) + t4z;
        __builtin_nontemporal_store(zero, o4 + o);
    }
}

extern "C" void kernel_launch(void* const* d_in, const int* in_sizes, int n_in,
                              void* d_out, int out_size, void* d_ws, size_t ws_size,
                              hipStream_t stream) {
    const float* x = (const float*)d_in[0];
    float* out = (float*)d_out;
    lhl_kernel<<<4096, 256, 0, stream>>>(x, out);   // 16384 wave-strips
}

// Round 9
// 136.244 us; speedup vs baseline: 1.2168x; 1.0479x over previous
//
#include <hip/hip_runtime.h>
#include <math.h>

// LogHarmonicLowering. floor(f + s_k) = f + D_k (constant integer offset per k).
// R9: R6's NT register pipeline + cross-strip software pipelining: each wave
// loads BOTH halves of its 9-row window (18 quads) up front, then stores half A
// then half B -> B's loads hide under A's stores, keeping HBM reads
// continuously in flight instead of bursty per-strip. NT stores (R7 proved
// cached regresses), reference-exact floorf weights (R8's constants not needed).

#define CH   16
#define KK   5
#define FREQ 1024

typedef float f32x4 __attribute__((ext_vector_type(4)));

__device__ __constant__ const float S_TAB[5] = {
    0.0f, 138.62943611198906f, 219.72245773362196f, 277.2588722239781f, 321.88758248682006f
};
#define D1 138
#define D2 219
#define D3 277
#define D4 321

__global__ __launch_bounds__(256) void lhl_kernel(const float* __restrict__ x,
                                                  float* __restrict__ out) {
    const int tid  = (int)threadIdx.x;
    const int wave = tid >> 6, lane = tid & 63;
    const int bi   = (int)blockIdx.x;

    // wave task: one (slice, jwin) 9-row window, both halves. 64*128 = 8192 waves.
    const int w     = bi * 4 + wave;
    const int jwin  = w & 127;              // input rows [8*jwin, 8*jwin+9)
    const int slice = w >> 7;               // b*16 + c
    const int b = slice >> 4, c = slice & 15;
    const int a = jwin << 3;

    const f32x4* __restrict__ xin = (const f32x4*)x;
    f32x4* __restrict__ o4 = (f32x4*)out;
    const size_t sbase = (size_t)slice << 17;

    // ---- issue ALL 18 loads first (halves A: cols 0..63, B: cols 64..127) ----
    f32x4 ra[9], rb[9];
    #pragma unroll
    for (int r = 0; r < 9; ++r) {
        const size_t rowb = sbase + ((size_t)min(a + r, FREQ - 1) << 7);
        ra[r] = xin[rowb + lane];
        rb[r] = xin[rowb + 64 + lane];
    }

    size_t pb[KK];
    #pragma unroll
    for (int k = 0; k < KK; ++k)
        pb[k] = (size_t)((b * KK + k) * CH + c) << 17;

    const int dtab[KK] = {0, D1, D2, D3, D4};

    // ---- stores: half A fully, then half B (B loads in flight under A stores) ----
    #pragma unroll
    for (int h = 0; h < 2; ++h) {
        const int col = (h << 6) + lane;
        #pragma unroll
        for (int r = 0; r < 8; ++r) {
            const int i0 = a + r;
            const f32x4 g0 = h ? rb[r] : ra[r];
            const f32x4 g1 = h ? rb[r + 1] : ra[r + 1];
            #pragma unroll
            for (int k = 0; k < KK; ++k) {
                const int f = i0 - dtab[k];
                if (f >= 0) {                          // wave-uniform
                    float pos = (float)f + S_TAB[k];
                    float w0 = pos - floorf(pos);      // reference-exact f32 frac
                    float w1 = (i0 + 1 < FREQ) ? w0 : 0.0f;
                    f32x4 res = g0 * (1.0f - w0) + g1 * w1;
                    __builtin_nontemporal_store(res, o4 + pb[k] + ((size_t)f << 7) + col);
                }
            }
        }
    }

    // ---- zero tail: 955 rows * 128 f4 per slice, 32 blocks/slice * 3820 ----
    const int blkin = bi & 31;
    const f32x4 zero = {0.f, 0.f, 0.f, 0.f};
    for (int l = tid; l < 3820; l += 256) {
        int zz = blkin * 3820 + l;
        int zrow = zz >> 7, t4z = zz & 127;
        int k, f;
        if (zrow < 138)      { k = 1; f = (FREQ - D1) + zrow; }
        else if (zrow < 357) { k = 2; f = (FREQ - D2) + (zrow - 138); }
        else if (zrow < 634) { k = 3; f = (FREQ - D3) + (zrow - 357); }
        else                 { k = 4; f = (FREQ - D4) + (zrow - 634); }
        __builtin_nontemporal_store(zero, o4 + pb[k] + ((size_t)f << 7) + t4z);
    }
}

extern "C" void kernel_launch(void* const* d_in, const int* in_sizes, int n_in,
                              void* d_out, int out_size, void* d_ws, size_t ws_size,
                              hipStream_t stream) {
    const float* x = (const float*)d_in[0];
    float* out = (float*)d_out;
    lhl_kernel<<<2048, 256, 0, stream>>>(x, out);   // 8192 window-waves
}